// Round 8
// baseline (94.211 us; speedup 1.0000x reference)
//
#include <hip/hip_runtime.h>

#define N_NODES 50000
#define IN_DIM 64
#define OUT_DIM 128
#define N_EDGES 800000

#define NBLK 128                    // partition blocks
#define EPB (N_EDGES / NBLK)        // 6250 edges per block (exact)
#define NBUCK 196                   // ceil(50000/256) buckets of 256 dsts
#define NSTRIP (N_NODES / 16)       // 3125 16-node strips (exact)
#define WLDS 136                    // padded bf16 row stride: bank step 4 -> 2-way (free)
#define HALF 25000                  // src-space split: each half = 3.2 MB bf16 rows < 4 MB L2

typedef __attribute__((ext_vector_type(8))) short bf16x8;
typedef __attribute__((ext_vector_type(4))) float f32x4;
typedef __attribute__((ext_vector_type(2))) float f32x2;

__device__ __forceinline__ unsigned short f2bf(float f) {
    unsigned u = __float_as_uint(f);
    unsigned r = u + 0x7FFFu + ((u >> 16) & 1u);   // round-to-nearest-even
    return (unsigned short)(r >> 16);
}

// ---------------- A0: per-(block,bucket) histogram + x->bf16 + W2->bf16 ----------------
__global__ __launch_bounds__(256) void bucket_count_cvt(const int* __restrict__ ei,
                                                        const float* __restrict__ x,
                                                        const float* __restrict__ Wl,
                                                        const float* __restrict__ Wr,
                                                        int* __restrict__ cnt_mat,
                                                        unsigned short* __restrict__ xh,
                                                        unsigned short* __restrict__ w2h)
{
    __shared__ int h[NBUCK];
    int t = threadIdx.x, blk = blockIdx.x;
    for (int i = t; i < NBUCK; i += 256) h[i] = 0;
    __syncthreads();
    int s = blk * EPB;
    for (int i = s + t; i < s + EPB; i += 256)
        atomicAdd(&h[ei[N_EDGES + i] >> 8], 1);
    // fused: convert this block's slice of x to bf16
    for (int i = t; i < 6250; i += 256) {
        int gi = blk * 6250 + i;
        float4 v = ((const float4*)x)[gi];
        ushort4 o;
        o.x = f2bf(v.x); o.y = f2bf(v.y); o.z = f2bf(v.z); o.w = f2bf(v.w);
        ((ushort4*)xh)[gi] = o;
    }
    // fused: W2h[o] = [Wr[o] | Wl[o]] in bf16 (block blk handles o=blk)
    if (t < 64) {
        w2h[blk * 128 + t]      = f2bf(Wr[blk * 64 + t]);
        w2h[blk * 128 + 64 + t] = f2bf(Wl[blk * 64 + t]);
    }
    __syncthreads();
    for (int b = t; b < NBUCK; b += 256) cnt_mat[b * NBLK + blk] = h[b];
}

// ---------------- scan: each block redundantly computes bucket starts in LDS;
// its 4 waves then scan their cnt_mat rows into per-(bucket,block) cursors.
__global__ __launch_bounds__(256) void rowscan(int* __restrict__ cnt_mat)
{
    __shared__ int tot[NBUCK];
    __shared__ int bst[NBUCK];
    __shared__ int ws[4];
    int t = threadIdx.x, lane = t & 63, wid = t >> 6;
    if (t < NBUCK) {
        const int4* row = (const int4*)(cnt_mat + t * NBLK);
        int sum = 0;
#pragma unroll 8
        for (int i = 0; i < NBLK / 4; ++i) { int4 v = row[i]; sum += v.x + v.y + v.z + v.w; }
        tot[t] = sum;
    }
    __syncthreads();
    int v = (t < NBUCK) ? tot[t] : 0;
    int incl = v;
#pragma unroll
    for (int d = 1; d < 64; d <<= 1) {
        int u = __shfl_up(incl, d, 64);
        if (lane >= d) incl += u;
    }
    if (lane == 63) ws[wid] = incl;
    __syncthreads();
    int woff = 0;
    for (int w = 0; w < wid; ++w) woff += ws[w];
    if (t < NBUCK) bst[t] = woff + incl - v;
    __syncthreads();
    int b = blockIdx.x * 4 + wid;
    if (b >= NBUCK) return;
    int base = bst[b];
#pragma unroll
    for (int c = 0; c < 2; ++c) {
        int idx = c * 64 + lane;
        int cv = cnt_mat[b * NBLK + idx];
        int ic = cv;
#pragma unroll
        for (int d = 1; d < 64; d <<= 1) {
            int u = __shfl_up(ic, d, 64);
            if (lane >= d) ic += u;
        }
        cnt_mat[b * NBLK + idx] = base + ic - cv;
        base += __shfl(ic, 63, 64);
    }
}

// ---------------- A1: partition edges into bucket-contiguous packed ebuf ----------------
// pack = src (16b) | dst_local (8b) << 16   (src < 50000 < 65536)
__global__ __launch_bounds__(256) void bucket_place(const int* __restrict__ ei,
                                                    const int* __restrict__ cnt_scan,
                                                    unsigned* __restrict__ ebuf)
{
    __shared__ int cur[NBUCK];
    int t = threadIdx.x, blk = blockIdx.x;
    for (int b = t; b < NBUCK; b += 256) cur[b] = cnt_scan[b * NBLK + blk];
    __syncthreads();
    int s = blk * EPB;
    for (int i = s + t; i < s + EPB; i += 256) {
        int src = ei[i], dst = ei[N_EDGES + i];
        int slot = atomicAdd(&cur[dst >> 8], 1);
        ebuf[slot] = (unsigned)src | ((unsigned)(dst & 255) << 16);
    }
}

// ---------------- B: final CSR within each bucket, split by src-half ----------------
// Per node: [start, mid) holds srcs < HALF, [mid, end) holds srcs >= HALF.
__global__ __launch_bounds__(256) void bucket_bin2(const unsigned* __restrict__ ebuf,
                                                   const int* __restrict__ cnt_scan,
                                                   unsigned short* __restrict__ srcs,
                                                   int* __restrict__ offs,
                                                   int* __restrict__ midv)
{
    __shared__ int h[512];
    __shared__ int cur[512];
    __shared__ int ws2[4];
    __shared__ int range_s[2];
    int t = threadIdx.x, b = blockIdx.x;
    int lane = t & 63, wid = t >> 6;
    if (t == 0) {
        range_s[0] = cnt_scan[b * NBLK];
        range_s[1] = (b < NBUCK - 1) ? cnt_scan[(b + 1) * NBLK] : N_EDGES;
    }
    h[t] = 0; h[t + 256] = 0;
    __syncthreads();
    int bs = range_s[0], be = range_s[1];
    for (int i = bs + t; i < be; i += 256) {
        unsigned p = ebuf[i];
        int dl = (p >> 16) & 255;
        int hf = ((p & 0xFFFFu) >= HALF) ? 1 : 0;
        atomicAdd(&h[dl * 2 + hf], 1);
    }
    __syncthreads();
    int h0 = h[t * 2], h1 = h[t * 2 + 1];
    int v = h0 + h1;
    int incl = v;
#pragma unroll
    for (int d = 1; d < 64; d <<= 1) {
        int u = __shfl_up(incl, d, 64);
        if (lane >= d) incl += u;
    }
    if (lane == 63) ws2[wid] = incl;
    __syncthreads();
    int woff = 0;
    for (int w = 0; w < wid; ++w) woff += ws2[w];
    incl += woff;
    int ex = incl - v;                 // node-exclusive offset within bucket
    cur[t * 2]     = bs + ex;
    cur[t * 2 + 1] = bs + ex + h0;
    int node = b * 256 + t;
    if (node < N_NODES) {
        offs[node] = bs + incl;        // end of node's list
        midv[node] = bs + ex + h0;     // boundary between halves
    }
    __syncthreads();
    for (int i = bs + t; i < be; i += 256) {
        unsigned p = ebuf[i];
        int dl = (p >> 16) & 255;
        unsigned srcv = p & 0xFFFFu;
        int hf = (srcv >= HALF) ? 1 : 0;
        int pos = atomicAdd(&cur[dl * 2 + hf], 1);
        srcs[pos] = (unsigned short)srcv;
    }
}

// ---------------- gather pass A: srcs < HALF only (xh_lo = 3.2 MB, L2-resident) ----
// Writes raw f32 partial sums into pacc (aliased over d_out; nontemporal).
__global__ __launch_bounds__(256) void gather_a(const unsigned short* __restrict__ xh,
                                                const int* __restrict__ offs,
                                                const int* __restrict__ midv,
                                                const unsigned short* __restrict__ srcs,
                                                float* __restrict__ pacc)
{
    int n = (blockIdx.x * 256 + threadIdx.x) >> 6;
    int lane = threadIdx.x & 63;
    if (n >= N_NODES) return;
    int half = lane >> 5;
    int fl = lane & 31;
    int start = n ? offs[n - 1] : 0;
    int end = midv[n];
    float a0 = 0.f, a1 = 0.f;
    for (int j = start; j < end; j += 64) {
        int m = end - j; if (m > 64) m = 64;
        int sv = (lane < m) ? (int)srcs[j + lane] : 0;
        for (int k = 0; k < m; k += 8) {
            int e0 = k + half, e1 = k + 2 + half, e2 = k + 4 + half, e3 = k + 6 + half;
            int s0 = __shfl(sv, e0, 64);
            int s1 = __shfl(sv, e1, 64);
            int s2 = __shfl(sv, e2, 64);
            int s3 = __shfl(sv, e3, 64);
            unsigned u0 = *(const unsigned*)(xh + (size_t)s0 * IN_DIM + fl * 2);
            unsigned u1 = *(const unsigned*)(xh + (size_t)s1 * IN_DIM + fl * 2);
            unsigned u2 = *(const unsigned*)(xh + (size_t)s2 * IN_DIM + fl * 2);
            unsigned u3 = *(const unsigned*)(xh + (size_t)s3 * IN_DIM + fl * 2);
            a0 += (e0 < m) ? __uint_as_float(u0 << 16) : 0.f;
            a1 += (e0 < m) ? __uint_as_float(u0 & 0xFFFF0000u) : 0.f;
            a0 += (e1 < m) ? __uint_as_float(u1 << 16) : 0.f;
            a1 += (e1 < m) ? __uint_as_float(u1 & 0xFFFF0000u) : 0.f;
            a0 += (e2 < m) ? __uint_as_float(u2 << 16) : 0.f;
            a1 += (e2 < m) ? __uint_as_float(u2 & 0xFFFF0000u) : 0.f;
            a0 += (e3 < m) ? __uint_as_float(u3 << 16) : 0.f;
            a1 += (e3 < m) ? __uint_as_float(u3 & 0xFFFF0000u) : 0.f;
        }
    }
    a0 += __shfl_xor(a0, 32, 64);
    a1 += __shfl_xor(a1, 32, 64);
    if (lane < 32) {
        f32x2 pv = {a0, a1};
        __builtin_nontemporal_store(pv, (f32x2*)(pacc + (size_t)n * IN_DIM + fl * 2));
    }
}

// ---------------- gather pass B: srcs >= HALF (xh_hi L2-resident), finalize mean ----
__global__ __launch_bounds__(256) void gather_b(const unsigned short* __restrict__ xh,
                                                const int* __restrict__ offs,
                                                const int* __restrict__ midv,
                                                const unsigned short* __restrict__ srcs,
                                                const float* __restrict__ pacc,
                                                unsigned short* __restrict__ meanh)
{
    int n = (blockIdx.x * 256 + threadIdx.x) >> 6;
    int lane = threadIdx.x & 63;
    if (n >= N_NODES) return;
    int half = lane >> 5;
    int fl = lane & 31;
    int start0 = n ? offs[n - 1] : 0;
    int start = midv[n];
    int end = offs[n];
    float a0 = 0.f, a1 = 0.f;
    for (int j = start; j < end; j += 64) {
        int m = end - j; if (m > 64) m = 64;
        int sv = (lane < m) ? (int)srcs[j + lane] : 0;
        for (int k = 0; k < m; k += 8) {
            int e0 = k + half, e1 = k + 2 + half, e2 = k + 4 + half, e3 = k + 6 + half;
            int s0 = __shfl(sv, e0, 64);
            int s1 = __shfl(sv, e1, 64);
            int s2 = __shfl(sv, e2, 64);
            int s3 = __shfl(sv, e3, 64);
            unsigned u0 = *(const unsigned*)(xh + (size_t)s0 * IN_DIM + fl * 2);
            unsigned u1 = *(const unsigned*)(xh + (size_t)s1 * IN_DIM + fl * 2);
            unsigned u2 = *(const unsigned*)(xh + (size_t)s2 * IN_DIM + fl * 2);
            unsigned u3 = *(const unsigned*)(xh + (size_t)s3 * IN_DIM + fl * 2);
            a0 += (e0 < m) ? __uint_as_float(u0 << 16) : 0.f;
            a1 += (e0 < m) ? __uint_as_float(u0 & 0xFFFF0000u) : 0.f;
            a0 += (e1 < m) ? __uint_as_float(u1 << 16) : 0.f;
            a1 += (e1 < m) ? __uint_as_float(u1 & 0xFFFF0000u) : 0.f;
            a0 += (e2 < m) ? __uint_as_float(u2 << 16) : 0.f;
            a1 += (e2 < m) ? __uint_as_float(u2 & 0xFFFF0000u) : 0.f;
            a0 += (e3 < m) ? __uint_as_float(u3 << 16) : 0.f;
            a1 += (e3 < m) ? __uint_as_float(u3 & 0xFFFF0000u) : 0.f;
        }
    }
    a0 += __shfl_xor(a0, 32, 64);
    a1 += __shfl_xor(a1, 32, 64);
    int deg = end - start0;
    float inv = deg ? 1.0f / (float)deg : 0.0f;
    if (lane < 32) {
        f32x2 pv = __builtin_nontemporal_load((const f32x2*)(pacc + (size_t)n * IN_DIM + fl * 2));
        float m0 = (a0 + pv[0]) * inv;
        float m1 = (a1 + pv[1]) * inv;
        unsigned mh = (unsigned)f2bf(m0) | ((unsigned)f2bf(m1) << 16);
        __builtin_nontemporal_store(mh, (unsigned*)(meanh + (size_t)n * IN_DIM + fl * 2));
    }
}

// ---------------- MFMA linear: out = [xh|meanh] @ W2h^T + b ----------------
__global__ __launch_bounds__(256) void sage_mfma(
    const unsigned short* __restrict__ xh, const unsigned short* __restrict__ meanh,
    const unsigned short* __restrict__ w2h, const float* __restrict__ bl,
    float* __restrict__ out)
{
    __shared__ unsigned short wlds[128 * WLDS];   // 34.8 KB
    int t = threadIdx.x;
#pragma unroll
    for (int c = 0; c < 8; ++c) {
        int idx = c * 256 + t;          // 2048 chunks of 8 bf16
        int o = idx >> 4, kc = idx & 15;
        bf16x8 v = *(const bf16x8*)(w2h + o * 128 + kc * 8);
        *(bf16x8*)(&wlds[o * WLDS + kc * 8]) = v;
    }
    __syncthreads();

    int wid = t >> 6, lane = t & 63;
    int strip = blockIdx.x * 4 + wid;
    if (strip >= NSTRIP) return;
    int nbase = strip * 16;
    int row = lane & 15, q = lane >> 4;

    const unsigned short* xrow = xh    + (size_t)(nbase + row) * IN_DIM + q * 8;
    const unsigned short* mrow = meanh + (size_t)(nbase + row) * IN_DIM + q * 8;
    bf16x8 a[4];
    a[0] = *(const bf16x8*)(xrow);
    a[1] = *(const bf16x8*)(xrow + 32);
    a[2] = *(const bf16x8*)(mrow);
    a[3] = *(const bf16x8*)(mrow + 32);

    f32x4 acc[8];
#pragma unroll
    for (int ot = 0; ot < 8; ++ot) acc[ot] = (f32x4){0.f, 0.f, 0.f, 0.f};

#pragma unroll
    for (int ot = 0; ot < 8; ++ot) {
        const unsigned short* wb = &wlds[(ot * 16 + row) * WLDS + q * 8];
#pragma unroll
        for (int s = 0; s < 4; ++s) {
            bf16x8 b = *(const bf16x8*)(wb + s * 32);
            acc[ot] = __builtin_amdgcn_mfma_f32_16x16x32_bf16(a[s], b, acc[ot], 0, 0, 0);
        }
    }

#pragma unroll
    for (int ot = 0; ot < 8; ++ot) {
        float bias = bl[ot * 16 + row];
#pragma unroll
        for (int r = 0; r < 4; ++r) {
            int n = nbase + q * 4 + r;
            out[(size_t)n * OUT_DIM + ot * 16 + row] = acc[ot][r] + bias;
        }
    }
}

extern "C" void kernel_launch(void* const* d_in, const int* in_sizes, int n_in,
                              void* d_out, int out_size, void* d_ws, size_t ws_size,
                              hipStream_t stream) {
    const float* x  = (const float*)d_in[0];
    const int*   ei = (const int*)d_in[1];
    const float* Wl = (const float*)d_in[2];
    const float* bl = (const float*)d_in[3];
    const float* Wr = (const float*)d_in[4];
    float* out = (float*)d_out;

    // ws layout (~18.1 MB):
    int*            cnt_mat = (int*)d_ws;                               // 25088 ints
    unsigned*       ebuf    = (unsigned*)(cnt_mat + NBUCK * NBLK);      // 800000 uints
    int*            offs    = (int*)(ebuf + N_EDGES);                   // 50000 ints
    int*            midv    = offs + N_NODES;                           // 50000 ints
    unsigned short* xh      = (unsigned short*)(midv + N_NODES);        // 3.2M bf16
    unsigned short* meanh   = xh + (size_t)N_NODES * IN_DIM;            // 3.2M bf16
    unsigned short* w2h     = meanh + (size_t)N_NODES * IN_DIM;         // 16384 bf16
    unsigned short* srcs    = w2h + 128 * 128;                          // 800000 ushort

    // pacc: f32 partial sums, 12.8 MB, aliased over d_out (dead until sage_mfma).
    float* pacc = out;

    bucket_count_cvt<<<NBLK, 256, 0, stream>>>(ei, x, Wl, Wr, cnt_mat, xh, w2h);
    rowscan<<<(NBUCK + 3) / 4, 256, 0, stream>>>(cnt_mat);
    bucket_place<<<NBLK, 256, 0, stream>>>(ei, cnt_mat, ebuf);
    bucket_bin2<<<NBUCK, 256, 0, stream>>>(ebuf, cnt_mat, srcs, offs, midv);

    int gb = (N_NODES * 64 + 255) / 256;            // 12500
    gather_a<<<gb, 256, 0, stream>>>(xh, offs, midv, srcs, pacc);
    gather_b<<<gb, 256, 0, stream>>>(xh, offs, midv, srcs, pacc, meanh);

    int mb = (NSTRIP + 3) / 4;                      // 782
    sage_mfma<<<mb, 256, 0, stream>>>(xh, meanh, w2h, bl, out);
}